// Round 2
// baseline (783.826 us; speedup 1.0000x reference)
//
#include <hip/hip_runtime.h>
#include <hip/hip_bf16.h>

// MHGCN: out = 0.5*(U1+U2), U1 = S@(feat@W1)+b1, U2 = S@(U1@W2)+b2,
// S = temp + temp^T, temp = einsum('ijk,kl->ij', A_stack, weight_b)
// N=8192, NFEAT=OUT=64.
//
// Pipeline:
//  1) k_sym_build: A_stack (1.34 GB, read once, nontemporal, dwordx4) -> S bf16 [N][N]
//  2) k_small_gemm_t: feature@W1 -> H1t bf16 [64][N]
//  3) k_gemm_skinny<0>: U1 = S@H1 + b1 — direct-load MFMA, no LDS staging, no
//     main-loop barriers; 4 waves = 4-way K-split, LDS reduce at end.
//  4) k_small_gemm_t: U1@W2 -> H2t
//  5) k_gemm_skinny<1>: out = 0.5*(U1 + S@H2 + b2)

#define NN 8192

typedef __attribute__((ext_vector_type(8))) short short8;
typedef __attribute__((ext_vector_type(8))) unsigned short u16x8;
typedef __attribute__((ext_vector_type(4))) unsigned short u16x4;
typedef __attribute__((ext_vector_type(4))) float f32x4;

static __device__ __forceinline__ unsigned short f2bf(float f) {
    unsigned u = __float_as_uint(f);
    u += 0x7FFFu + ((u >> 16) & 1u);     // round-to-nearest-even
    return (unsigned short)(u >> 16);
}

// ---------------------------------------------------------------------------
// 1) S = temp + temp^T (bf16). Upper-tri 64x64 tile pairs; A read exactly once.
//    Quad-element threads: 5x dwordx4 (16B-aligned, 80B stride) nontemporal
//    loads per 4 elements; u16x4 stores.
// ---------------------------------------------------------------------------
__global__ __launch_bounds__(256) void k_sym_build(
        const float* __restrict__ A, const float* __restrict__ wb,
        unsigned short* __restrict__ S) {
    __shared__ float Tt[64 * 65];

    int b = blockIdx.x;
    // decode linear id -> (bi, bj), bi <= bj, 128x128 tiles
    double disc = 66049.0 - 8.0 * (double)b;
    int bi = (int)((257.0 - sqrt(disc)) * 0.5);
    if (bi < 0) bi = 0; if (bi > 127) bi = 127;
    while (bi < 127 && (bi + 1) * (257 - (bi + 1)) / 2 <= b) ++bi;
    while (bi > 0 && bi * (257 - bi) / 2 > b) --bi;
    int bj = bi + (b - bi * (257 - bi) / 2);

    const float w0 = wb[0], w1 = wb[1], w2 = wb[2], w3 = wb[3], w4 = wb[4];
    int t = threadIdx.x;
    int qc = t & 15;          // quad-col: cols 4*qc .. 4*qc+3
    int r0 = t >> 4;          // rows r0 + 16*e

    float t1[4][4];
    #pragma unroll
    for (int e = 0; e < 4; ++e) {
        int r = r0 + 16 * e;
        {   // tile1: (bi,bj) row r
            const f32x4* p = (const f32x4*)(A +
                ((long long)(bi * 64 + r) * NN + bj * 64 + 4 * qc) * 5);
            f32x4 f0 = __builtin_nontemporal_load(p);
            f32x4 f1 = __builtin_nontemporal_load(p + 1);
            f32x4 f2 = __builtin_nontemporal_load(p + 2);
            f32x4 f3 = __builtin_nontemporal_load(p + 3);
            f32x4 f4 = __builtin_nontemporal_load(p + 4);
            t1[e][0] = f0[0]*w0 + f0[1]*w1 + f0[2]*w2 + f0[3]*w3 + f1[0]*w4;
            t1[e][1] = f1[1]*w0 + f1[2]*w1 + f1[3]*w2 + f2[0]*w3 + f2[1]*w4;
            t1[e][2] = f2[2]*w0 + f2[3]*w1 + f3[0]*w2 + f3[1]*w3 + f3[2]*w4;
            t1[e][3] = f3[3]*w0 + f4[0]*w1 + f4[1]*w2 + f4[2]*w3 + f4[3]*w4;
        }
        {   // tile2: (bj,bi) row r -> LDS row-major
            const f32x4* p = (const f32x4*)(A +
                ((long long)(bj * 64 + r) * NN + bi * 64 + 4 * qc) * 5);
            f32x4 f0 = __builtin_nontemporal_load(p);
            f32x4 f1 = __builtin_nontemporal_load(p + 1);
            f32x4 f2 = __builtin_nontemporal_load(p + 2);
            f32x4 f3 = __builtin_nontemporal_load(p + 3);
            f32x4 f4 = __builtin_nontemporal_load(p + 4);
            Tt[r * 65 + 4*qc + 0] = f0[0]*w0 + f0[1]*w1 + f0[2]*w2 + f0[3]*w3 + f1[0]*w4;
            Tt[r * 65 + 4*qc + 1] = f1[1]*w0 + f1[2]*w1 + f1[3]*w2 + f2[0]*w3 + f2[1]*w4;
            Tt[r * 65 + 4*qc + 2] = f2[2]*w0 + f2[3]*w1 + f3[0]*w2 + f3[1]*w3 + f3[2]*w4;
            Tt[r * 65 + 4*qc + 3] = f3[3]*w0 + f4[0]*w1 + f4[1]*w2 + f4[2]*w3 + f4[3]*w4;
        }
    }
    __syncthreads();
    float sv[4][4];
    #pragma unroll
    for (int e = 0; e < 4; ++e) {
        int r = r0 + 16 * e;
        u16x4 o;
        #pragma unroll
        for (int q = 0; q < 4; ++q) {
            float v = t1[e][q] + Tt[(4*qc + q) * 65 + r];   // T1[i][j] + T2[j][i]
            sv[e][q] = v;
            o[q] = f2bf(v);
        }
        *(u16x4*)(S + (long long)(bi * 64 + r) * NN + bj * 64 + 4 * qc) = o;
    }
    __syncthreads();
    #pragma unroll
    for (int e = 0; e < 4; ++e) {
        int r = r0 + 16 * e;
        #pragma unroll
        for (int q = 0; q < 4; ++q) Tt[r * 65 + 4*qc + q] = sv[e][q];
    }
    __syncthreads();
    if (bi != bj) {
        #pragma unroll
        for (int e = 0; e < 4; ++e) {
            int r = r0 + 16 * e;      // row within mirror tile
            u16x4 o;
            #pragma unroll
            for (int q = 0; q < 4; ++q) o[q] = f2bf(Tt[(4*qc + q) * 65 + r]);
            *(u16x4*)(S + (long long)(bj * 64 + r) * NN + bi * 64 + 4 * qc) = o;
        }
    }
}

// ---------------------------------------------------------------------------
// 2/4) Yt[c][row] = sum_k X[row][k]*W[k][c]   (bf16, transposed output)
// ---------------------------------------------------------------------------
__global__ __launch_bounds__(256) void k_small_gemm_t(
        const float* __restrict__ X, const float* __restrict__ W,
        unsigned short* __restrict__ Yt) {
    __shared__ float Ys[64 * 65];
    int t = threadIdx.x, lane = t & 63, w = t >> 6;
    float wcol[64];                       // this lane's W column
    #pragma unroll
    for (int k = 0; k < 64; ++k) wcol[k] = W[k * 64 + lane];
    int r0 = blockIdx.x * 64;
    for (int rr = 0; rr < 16; ++rr) {
        const f32x4* x = (const f32x4*)(X + (long long)(r0 + w * 16 + rr) * 64);
        float acc = 0.f;
        #pragma unroll
        for (int k4 = 0; k4 < 16; ++k4) {
            f32x4 xv = x[k4];
            acc += xv[0]*wcol[4*k4] + xv[1]*wcol[4*k4+1]
                 + xv[2]*wcol[4*k4+2] + xv[3]*wcol[4*k4+3];
        }
        Ys[lane * 65 + w * 16 + rr] = acc;    // Ys[col][row-in-tile]
    }
    __syncthreads();
    int c = t >> 2, j0 = (t & 3) * 16;
    u16x8 o0, o1;
    #pragma unroll
    for (int q = 0; q < 8; ++q) {
        o0[q] = f2bf(Ys[c * 65 + j0 + q]);
        o1[q] = f2bf(Ys[c * 65 + j0 + 8 + q]);
    }
    *(u16x8*)(Yt + (long long)c * NN + r0 + j0) = o0;
    *(u16x8*)(Yt + (long long)c * NN + r0 + j0 + 8) = o1;
}

// ---------------------------------------------------------------------------
// 3/5) Y[i][f] = (FINAL? 0.5*(U1+.) : .)(bias[f] + sum_j S[i][j]*H[j][f])
//   Direct-load MFMA: a-frag u16x8 from S, b-frags u16x8 from Ht, no LDS
//   staging, no main-loop barriers. 4 waves = 4-way K-split; LDS reduce.
// ---------------------------------------------------------------------------
template<int FINAL>
__global__ __launch_bounds__(256) void k_gemm_skinny(
        const unsigned short* __restrict__ S,
        const unsigned short* __restrict__ Ht,   // [64][NN]
        const float* __restrict__ bias,
        const float* __restrict__ U1,
        float* __restrict__ Y) {
    __shared__ float red[4][16][64];   // 16 KB
    int t = threadIdx.x;
    int lane = t & 63, w = t >> 6;     // w = K-quarter
    int i0 = blockIdx.x * 16;
    int r = lane & 15, kg = lane >> 4;

    const unsigned short* aRow = S + (long long)(i0 + r) * NN + kg * 8;
    const unsigned short* bRow = Ht + (long long)r * NN + kg * 8;
    f32x4 acc0 = {0,0,0,0}, acc1 = {0,0,0,0}, acc2 = {0,0,0,0}, acc3 = {0,0,0,0};

    int j0 = w * 2048;
    for (int jt = j0; jt < j0 + 2048; jt += 128) {
        #pragma unroll
        for (int kk = 0; kk < 4; ++kk) {
            int off = jt + kk * 32;
            short8 a   = *(const short8*)(aRow + off);
            short8 bb0 = *(const short8*)(bRow + off);
            short8 bb1 = *(const short8*)(bRow + 16 * NN + off);
            short8 bb2 = *(const short8*)(bRow + 32 * NN + off);
            short8 bb3 = *(const short8*)(bRow + 48 * NN + off);
            acc0 = __builtin_amdgcn_mfma_f32_16x16x32_bf16(a, bb0, acc0, 0, 0, 0);
            acc1 = __builtin_amdgcn_mfma_f32_16x16x32_bf16(a, bb1, acc1, 0, 0, 0);
            acc2 = __builtin_amdgcn_mfma_f32_16x16x32_bf16(a, bb2, acc2, 0, 0, 0);
            acc3 = __builtin_amdgcn_mfma_f32_16x16x32_bf16(a, bb3, acc3, 0, 0, 0);
        }
    }
    // D[m = kg*4 + rr][n-col = r] per n-tile
    #pragma unroll
    for (int rr = 0; rr < 4; ++rr) {
        red[w][kg * 4 + rr][r]      = acc0[rr];
        red[w][kg * 4 + rr][16 + r] = acc1[rr];
        red[w][kg * 4 + rr][32 + r] = acc2[rr];
        red[w][kg * 4 + rr][48 + r] = acc3[rr];
    }
    __syncthreads();
    #pragma unroll
    for (int e = 0; e < 4; ++e) {
        int idx = t + e * 256;
        int m = idx >> 6, c = idx & 63;
        float v = red[0][m][c] + red[1][m][c] + red[2][m][c] + red[3][m][c] + bias[c];
        long long gi = (long long)(i0 + m) * 64 + c;
        if (FINAL) v = 0.5f * (U1[gi] + v);
        Y[gi] = v;
    }
}

// ---------------------------------------------------------------------------
extern "C" void kernel_launch(void* const* d_in, const int* in_sizes, int n_in,
                              void* d_out, int out_size, void* d_ws, size_t ws_size,
                              hipStream_t stream) {
    const float* A    = (const float*)d_in[0];
    const float* feat = (const float*)d_in[1];
    const float* wb   = (const float*)d_in[2];
    const float* W1   = (const float*)d_in[3];
    const float* b1   = (const float*)d_in[4];
    const float* W2   = (const float*)d_in[5];
    const float* b2   = (const float*)d_in[6];
    float* out = (float*)d_out;

    const size_t szS = (size_t)NN * NN * 2;       // 128 MB bf16 S
    const size_t szH = (size_t)64 * NN * 2;       // 1 MB  bf16 Ht
    char* p = (char*)d_ws;
    unsigned short* S   = (unsigned short*)p;
    unsigned short* H1t = (unsigned short*)(p + szS);
    unsigned short* H2t = (unsigned short*)(p + szS + szH);
    float*          U1  = (float*)(p + szS + 2 * szH);

    k_sym_build<<<8256, 256, 0, stream>>>(A, wb, S);
    k_small_gemm_t<<<128, 256, 0, stream>>>(feat, W1, H1t);
    k_gemm_skinny<0><<<512, 256, 0, stream>>>(S, H1t, b1, nullptr, U1);
    k_small_gemm_t<<<128, 256, 0, stream>>>(U1, W2, H2t);
    k_gemm_skinny<1><<<512, 256, 0, stream>>>(S, H2t, b2, U1, out);
}

// Round 3
// 501.794 us; speedup vs baseline: 1.5620x; 1.5620x over previous
//
#include <hip/hip_runtime.h>
#include <hip/hip_bf16.h>

// MHGCN: out = 0.5*(U1+U2), U1 = S@(feat@W1)+b1, U2 = S@(U1@W2)+b2,
// S = temp + temp^T, temp = einsum('ijk,kl->ij', A_stack, weight_b)
// N=8192, NFEAT=OUT=64.
//
// Pipeline:
//  1) k_sym_build: A_stack (1.34 GB, read once, CACHED dwordx4 — R1's
//     nontemporal hint defeated cache-line reuse of the stride-80B pattern
//     and cost +336us) -> S bf16 [N][N]
//  2) k_small_gemm_t: feature@W1 -> H1t bf16 [64][N]
//  3) k_gemm_skinny<0>: U1 = S@H1 + b1 — direct-load MFMA, no LDS staging.
//  4) k_small_gemm_t: U1@W2 -> H2t
//  5) k_gemm_skinny<1>: out = 0.5*(U1 + S@H2 + b2)

#define NN 8192

typedef __attribute__((ext_vector_type(8))) short short8;
typedef __attribute__((ext_vector_type(8))) unsigned short u16x8;
typedef __attribute__((ext_vector_type(4))) unsigned short u16x4;
typedef __attribute__((ext_vector_type(4))) float f32x4;

static __device__ __forceinline__ unsigned short f2bf(float f) {
    unsigned u = __float_as_uint(f);
    u += 0x7FFFu + ((u >> 16) & 1u);     // round-to-nearest-even
    return (unsigned short)(u >> 16);
}

// ---------------------------------------------------------------------------
// 1) S = temp + temp^T (bf16). Upper-tri 64x64 tile pairs; A read exactly once.
//    Quad-element threads: 5x dwordx4 (16B-aligned, 80B stride, normal cached)
//    loads per 4 elements; u16x4 stores.
// ---------------------------------------------------------------------------
__global__ __launch_bounds__(256) void k_sym_build(
        const float* __restrict__ A, const float* __restrict__ wb,
        unsigned short* __restrict__ S) {
    __shared__ float Tt[64 * 65];

    int b = blockIdx.x;
    // decode linear id -> (bi, bj), bi <= bj, 128x128 tiles
    double disc = 66049.0 - 8.0 * (double)b;
    int bi = (int)((257.0 - sqrt(disc)) * 0.5);
    if (bi < 0) bi = 0; if (bi > 127) bi = 127;
    while (bi < 127 && (bi + 1) * (257 - (bi + 1)) / 2 <= b) ++bi;
    while (bi > 0 && bi * (257 - bi) / 2 > b) --bi;
    int bj = bi + (b - bi * (257 - bi) / 2);

    const float w0 = wb[0], w1 = wb[1], w2 = wb[2], w3 = wb[3], w4 = wb[4];
    int t = threadIdx.x;
    int qc = t & 15;          // quad-col: cols 4*qc .. 4*qc+3
    int r0 = t >> 4;          // rows r0 + 16*e

    float t1[4][4];
    #pragma unroll
    for (int e = 0; e < 4; ++e) {
        int r = r0 + 16 * e;
        {   // tile1: (bi,bj) row r
            const f32x4* p = (const f32x4*)(A +
                ((long long)(bi * 64 + r) * NN + bj * 64 + 4 * qc) * 5);
            f32x4 f0 = p[0], f1 = p[1], f2 = p[2], f3 = p[3], f4 = p[4];
            t1[e][0] = f0[0]*w0 + f0[1]*w1 + f0[2]*w2 + f0[3]*w3 + f1[0]*w4;
            t1[e][1] = f1[1]*w0 + f1[2]*w1 + f1[3]*w2 + f2[0]*w3 + f2[1]*w4;
            t1[e][2] = f2[2]*w0 + f2[3]*w1 + f3[0]*w2 + f3[1]*w3 + f3[2]*w4;
            t1[e][3] = f3[3]*w0 + f4[0]*w1 + f4[1]*w2 + f4[2]*w3 + f4[3]*w4;
        }
        {   // tile2: (bj,bi) row r -> LDS row-major
            const f32x4* p = (const f32x4*)(A +
                ((long long)(bj * 64 + r) * NN + bi * 64 + 4 * qc) * 5);
            f32x4 f0 = p[0], f1 = p[1], f2 = p[2], f3 = p[3], f4 = p[4];
            Tt[r * 65 + 4*qc + 0] = f0[0]*w0 + f0[1]*w1 + f0[2]*w2 + f0[3]*w3 + f1[0]*w4;
            Tt[r * 65 + 4*qc + 1] = f1[1]*w0 + f1[2]*w1 + f1[3]*w2 + f2[0]*w3 + f2[1]*w4;
            Tt[r * 65 + 4*qc + 2] = f2[2]*w0 + f2[3]*w1 + f3[0]*w2 + f3[1]*w3 + f3[2]*w4;
            Tt[r * 65 + 4*qc + 3] = f3[3]*w0 + f4[0]*w1 + f4[1]*w2 + f4[2]*w3 + f4[3]*w4;
        }
    }
    __syncthreads();
    float sv[4][4];
    #pragma unroll
    for (int e = 0; e < 4; ++e) {
        int r = r0 + 16 * e;
        u16x4 o;
        #pragma unroll
        for (int q = 0; q < 4; ++q) {
            float v = t1[e][q] + Tt[(4*qc + q) * 65 + r];   // T1[i][j] + T2[j][i]
            sv[e][q] = v;
            o[q] = f2bf(v);
        }
        *(u16x4*)(S + (long long)(bi * 64 + r) * NN + bj * 64 + 4 * qc) = o;
    }
    __syncthreads();
    #pragma unroll
    for (int e = 0; e < 4; ++e) {
        int r = r0 + 16 * e;
        #pragma unroll
        for (int q = 0; q < 4; ++q) Tt[r * 65 + 4*qc + q] = sv[e][q];
    }
    __syncthreads();
    if (bi != bj) {
        #pragma unroll
        for (int e = 0; e < 4; ++e) {
            int r = r0 + 16 * e;      // row within mirror tile
            u16x4 o;
            #pragma unroll
            for (int q = 0; q < 4; ++q) o[q] = f2bf(Tt[(4*qc + q) * 65 + r]);
            *(u16x4*)(S + (long long)(bj * 64 + r) * NN + bi * 64 + 4 * qc) = o;
        }
    }
}

// ---------------------------------------------------------------------------
// 2/4) Yt[c][row] = sum_k X[row][k]*W[k][c]   (bf16, transposed output)
// ---------------------------------------------------------------------------
__global__ __launch_bounds__(256) void k_small_gemm_t(
        const float* __restrict__ X, const float* __restrict__ W,
        unsigned short* __restrict__ Yt) {
    __shared__ float Ys[64 * 65];
    int t = threadIdx.x, lane = t & 63, w = t >> 6;
    float wcol[64];                       // this lane's W column
    #pragma unroll
    for (int k = 0; k < 64; ++k) wcol[k] = W[k * 64 + lane];
    int r0 = blockIdx.x * 64;
    for (int rr = 0; rr < 16; ++rr) {
        const f32x4* x = (const f32x4*)(X + (long long)(r0 + w * 16 + rr) * 64);
        float acc = 0.f;
        #pragma unroll
        for (int k4 = 0; k4 < 16; ++k4) {
            f32x4 xv = x[k4];
            acc += xv[0]*wcol[4*k4] + xv[1]*wcol[4*k4+1]
                 + xv[2]*wcol[4*k4+2] + xv[3]*wcol[4*k4+3];
        }
        Ys[lane * 65 + w * 16 + rr] = acc;    // Ys[col][row-in-tile]
    }
    __syncthreads();
    int c = t >> 2, j0 = (t & 3) * 16;
    u16x8 o0, o1;
    #pragma unroll
    for (int q = 0; q < 8; ++q) {
        o0[q] = f2bf(Ys[c * 65 + j0 + q]);
        o1[q] = f2bf(Ys[c * 65 + j0 + 8 + q]);
    }
    *(u16x8*)(Yt + (long long)c * NN + r0 + j0) = o0;
    *(u16x8*)(Yt + (long long)c * NN + r0 + j0 + 8) = o1;
}

// ---------------------------------------------------------------------------
// 3/5) Y[i][f] = (FINAL? 0.5*(U1+.) : .)(bias[f] + sum_j S[i][j]*H[j][f])
//   Direct-load MFMA: a-frag u16x8 from S, b-frags u16x8 from Ht, no LDS
//   staging, no main-loop barriers. 4 waves = 4-way K-split; LDS reduce.
// ---------------------------------------------------------------------------
template<int FINAL>
__global__ __launch_bounds__(256) void k_gemm_skinny(
        const unsigned short* __restrict__ S,
        const unsigned short* __restrict__ Ht,   // [64][NN]
        const float* __restrict__ bias,
        const float* __restrict__ U1,
        float* __restrict__ Y) {
    __shared__ float red[4][16][64];   // 16 KB
    int t = threadIdx.x;
    int lane = t & 63, w = t >> 6;     // w = K-quarter
    int i0 = blockIdx.x * 16;
    int r = lane & 15, kg = lane >> 4;

    const unsigned short* aRow = S + (long long)(i0 + r) * NN + kg * 8;
    const unsigned short* bRow = Ht + (long long)r * NN + kg * 8;
    f32x4 acc0 = {0,0,0,0}, acc1 = {0,0,0,0}, acc2 = {0,0,0,0}, acc3 = {0,0,0,0};

    int j0 = w * 2048;
    for (int jt = j0; jt < j0 + 2048; jt += 128) {
        #pragma unroll
        for (int kk = 0; kk < 4; ++kk) {
            int off = jt + kk * 32;
            short8 a   = *(const short8*)(aRow + off);
            short8 bb0 = *(const short8*)(bRow + off);
            short8 bb1 = *(const short8*)(bRow + 16 * NN + off);
            short8 bb2 = *(const short8*)(bRow + 32 * NN + off);
            short8 bb3 = *(const short8*)(bRow + 48 * NN + off);
            acc0 = __builtin_amdgcn_mfma_f32_16x16x32_bf16(a, bb0, acc0, 0, 0, 0);
            acc1 = __builtin_amdgcn_mfma_f32_16x16x32_bf16(a, bb1, acc1, 0, 0, 0);
            acc2 = __builtin_amdgcn_mfma_f32_16x16x32_bf16(a, bb2, acc2, 0, 0, 0);
            acc3 = __builtin_amdgcn_mfma_f32_16x16x32_bf16(a, bb3, acc3, 0, 0, 0);
        }
    }
    // D[m = kg*4 + rr][n-col = r] per n-tile
    #pragma unroll
    for (int rr = 0; rr < 4; ++rr) {
        red[w][kg * 4 + rr][r]      = acc0[rr];
        red[w][kg * 4 + rr][16 + r] = acc1[rr];
        red[w][kg * 4 + rr][32 + r] = acc2[rr];
        red[w][kg * 4 + rr][48 + r] = acc3[rr];
    }
    __syncthreads();
    #pragma unroll
    for (int e = 0; e < 4; ++e) {
        int idx = t + e * 256;
        int m = idx >> 6, c = idx & 63;
        float v = red[0][m][c] + red[1][m][c] + red[2][m][c] + red[3][m][c] + bias[c];
        long long gi = (long long)(i0 + m) * 64 + c;
        if (FINAL) v = 0.5f * (U1[gi] + v);
        Y[gi] = v;
    }
}

// ---------------------------------------------------------------------------
extern "C" void kernel_launch(void* const* d_in, const int* in_sizes, int n_in,
                              void* d_out, int out_size, void* d_ws, size_t ws_size,
                              hipStream_t stream) {
    const float* A    = (const float*)d_in[0];
    const float* feat = (const float*)d_in[1];
    const float* wb   = (const float*)d_in[2];
    const float* W1   = (const float*)d_in[3];
    const float* b1   = (const float*)d_in[4];
    const float* W2   = (const float*)d_in[5];
    const float* b2   = (const float*)d_in[6];
    float* out = (float*)d_out;

    const size_t szS = (size_t)NN * NN * 2;       // 128 MB bf16 S
    const size_t szH = (size_t)64 * NN * 2;       // 1 MB  bf16 Ht
    char* p = (char*)d_ws;
    unsigned short* S   = (unsigned short*)p;
    unsigned short* H1t = (unsigned short*)(p + szS);
    unsigned short* H2t = (unsigned short*)(p + szS + szH);
    float*          U1  = (float*)(p + szS + 2 * szH);

    k_sym_build<<<8256, 256, 0, stream>>>(A, wb, S);
    k_small_gemm_t<<<128, 256, 0, stream>>>(feat, W1, H1t);
    k_gemm_skinny<0><<<512, 256, 0, stream>>>(S, H1t, b1, nullptr, U1);
    k_small_gemm_t<<<128, 256, 0, stream>>>(U1, W2, H2t);
    k_gemm_skinny<1><<<512, 256, 0, stream>>>(S, H2t, b2, U1, out);
}

// Round 4
// 445.342 us; speedup vs baseline: 1.7601x; 1.1268x over previous
//
#include <hip/hip_runtime.h>
#include <hip/hip_bf16.h>

// MHGCN: out = 0.5*(U1+U2), U1 = S@(feat@W1)+b1, U2 = S@(U1@W2)+b2,
// S = temp + temp^T (symmetric), temp = einsum('ijk,kl->ij', A_stack, weight_b)
// N=8192, NFEAT=OUT=64.
//
//  1) k_sym_build: A_stack (1.34 GB, read once) -> S bf16 [N][N]   (unchanged from R2)
//  2) k_small_gemm_t: feature@W1 -> H1t bf16 [64][N]
//  3) k_gemm_skinny<0>: U1 = S@H1 + b1 — global_load_lds double-buffered MFMA
//  4) k_small_gemm_t: U1@W2 -> H2t
//  5) k_gemm_skinny<1>: out = 0.5*(U1 + S@H2 + b2)

#define NN 8192

typedef __attribute__((ext_vector_type(8))) short short8;
typedef __attribute__((ext_vector_type(8))) unsigned short u16x8;
typedef __attribute__((ext_vector_type(4))) unsigned short u16x4;
typedef __attribute__((ext_vector_type(4))) float f32x4;

static __device__ __forceinline__ unsigned short f2bf(float f) {
    unsigned u = __float_as_uint(f);
    u += 0x7FFFu + ((u >> 16) & 1u);     // round-to-nearest-even
    return (unsigned short)(u >> 16);
}

#define GL16(gsrc, ldst) __builtin_amdgcn_global_load_lds( \
    (const __attribute__((address_space(1))) void*)(gsrc), \
    (__attribute__((address_space(3))) void*)(ldst), 16, 0, 0)

// ---------------------------------------------------------------------------
// 1) S = temp + temp^T (bf16). Upper-tri 64x64 tile pairs; A read exactly once.
// ---------------------------------------------------------------------------
__global__ __launch_bounds__(256) void k_sym_build(
        const float* __restrict__ A, const float* __restrict__ wb,
        unsigned short* __restrict__ S) {
    __shared__ float Tt[64 * 65];

    int b = blockIdx.x;
    double disc = 66049.0 - 8.0 * (double)b;
    int bi = (int)((257.0 - sqrt(disc)) * 0.5);
    if (bi < 0) bi = 0; if (bi > 127) bi = 127;
    while (bi < 127 && (bi + 1) * (257 - (bi + 1)) / 2 <= b) ++bi;
    while (bi > 0 && bi * (257 - bi) / 2 > b) --bi;
    int bj = bi + (b - bi * (257 - bi) / 2);

    const float w0 = wb[0], w1 = wb[1], w2 = wb[2], w3 = wb[3], w4 = wb[4];
    int t = threadIdx.x;
    int qc = t & 15;          // quad-col: cols 4*qc .. 4*qc+3
    int r0 = t >> 4;          // rows r0 + 16*e

    float t1[4][4];
    #pragma unroll
    for (int e = 0; e < 4; ++e) {
        int r = r0 + 16 * e;
        {   // tile1: (bi,bj) row r
            const f32x4* p = (const f32x4*)(A +
                ((long long)(bi * 64 + r) * NN + bj * 64 + 4 * qc) * 5);
            f32x4 f0 = p[0], f1 = p[1], f2 = p[2], f3 = p[3], f4 = p[4];
            t1[e][0] = f0[0]*w0 + f0[1]*w1 + f0[2]*w2 + f0[3]*w3 + f1[0]*w4;
            t1[e][1] = f1[1]*w0 + f1[2]*w1 + f1[3]*w2 + f2[0]*w3 + f2[1]*w4;
            t1[e][2] = f2[2]*w0 + f2[3]*w1 + f3[0]*w2 + f3[1]*w3 + f3[2]*w4;
            t1[e][3] = f3[3]*w0 + f4[0]*w1 + f4[1]*w2 + f4[2]*w3 + f4[3]*w4;
        }
        {   // tile2: (bj,bi) row r -> LDS row-major
            const f32x4* p = (const f32x4*)(A +
                ((long long)(bj * 64 + r) * NN + bi * 64 + 4 * qc) * 5);
            f32x4 f0 = p[0], f1 = p[1], f2 = p[2], f3 = p[3], f4 = p[4];
            Tt[r * 65 + 4*qc + 0] = f0[0]*w0 + f0[1]*w1 + f0[2]*w2 + f0[3]*w3 + f1[0]*w4;
            Tt[r * 65 + 4*qc + 1] = f1[1]*w0 + f1[2]*w1 + f1[3]*w2 + f2[0]*w3 + f2[1]*w4;
            Tt[r * 65 + 4*qc + 2] = f2[2]*w0 + f2[3]*w1 + f3[0]*w2 + f3[1]*w3 + f3[2]*w4;
            Tt[r * 65 + 4*qc + 3] = f3[3]*w0 + f4[0]*w1 + f4[1]*w2 + f4[2]*w3 + f4[3]*w4;
        }
    }
    __syncthreads();
    float sv[4][4];
    #pragma unroll
    for (int e = 0; e < 4; ++e) {
        int r = r0 + 16 * e;
        u16x4 o;
        #pragma unroll
        for (int q = 0; q < 4; ++q) {
            float v = t1[e][q] + Tt[(4*qc + q) * 65 + r];   // T1[i][j] + T2[j][i]
            sv[e][q] = v;
            o[q] = f2bf(v);
        }
        *(u16x4*)(S + (long long)(bi * 64 + r) * NN + bj * 64 + 4 * qc) = o;
    }
    __syncthreads();
    #pragma unroll
    for (int e = 0; e < 4; ++e) {
        int r = r0 + 16 * e;
        #pragma unroll
        for (int q = 0; q < 4; ++q) Tt[r * 65 + 4*qc + q] = sv[e][q];
    }
    __syncthreads();
    if (bi != bj) {
        #pragma unroll
        for (int e = 0; e < 4; ++e) {
            int r = r0 + 16 * e;
            u16x4 o;
            #pragma unroll
            for (int q = 0; q < 4; ++q) o[q] = f2bf(Tt[(4*qc + q) * 65 + r]);
            *(u16x4*)(S + (long long)(bj * 64 + r) * NN + bi * 64 + 4 * qc) = o;
        }
    }
}

// ---------------------------------------------------------------------------
// 2/4) Yt[c][row] = sum_k X[row][k]*W[k][c]   (bf16, transposed output)
// ---------------------------------------------------------------------------
__global__ __launch_bounds__(256) void k_small_gemm_t(
        const float* __restrict__ X, const float* __restrict__ W,
        unsigned short* __restrict__ Yt) {
    __shared__ float Ys[64 * 65];
    int t = threadIdx.x, lane = t & 63, w = t >> 6;
    float wcol[64];
    #pragma unroll
    for (int k = 0; k < 64; ++k) wcol[k] = W[k * 64 + lane];
    int r0 = blockIdx.x * 64;
    for (int rr = 0; rr < 16; ++rr) {
        const f32x4* x = (const f32x4*)(X + (long long)(r0 + w * 16 + rr) * 64);
        float acc = 0.f;
        #pragma unroll
        for (int k4 = 0; k4 < 16; ++k4) {
            f32x4 xv = x[k4];
            acc += xv[0]*wcol[4*k4] + xv[1]*wcol[4*k4+1]
                 + xv[2]*wcol[4*k4+2] + xv[3]*wcol[4*k4+3];
        }
        Ys[lane * 65 + w * 16 + rr] = acc;    // Ys[col][row-in-tile]
    }
    __syncthreads();
    int c = t >> 2, j0 = (t & 3) * 16;
    u16x8 o0, o1;
    #pragma unroll
    for (int q = 0; q < 8; ++q) {
        o0[q] = f2bf(Ys[c * 65 + j0 + q]);
        o1[q] = f2bf(Ys[c * 65 + j0 + 8 + q]);
    }
    *(u16x8*)(Yt + (long long)c * NN + r0 + j0) = o0;
    *(u16x8*)(Yt + (long long)c * NN + r0 + j0 + 8) = o1;
}

// ---------------------------------------------------------------------------
// 3/5) Y[i][f] = (FINAL? 0.5*(U1+.) : .)(bias[f] + sum_j S[i][j]*H[j][f])
//   global_load_lds (width 16) double-buffered staging; linear LDS dest with
//   pre-swizzled GLOBAL source (m173) so ds_read_b128 is XOR-bank-spread.
//   One __syncthreads per K-step; prefetch next tile before computing current.
//   Each wave owns one 16-col n-strip for all 16 rows -> acc is final.
// ---------------------------------------------------------------------------
template<int FINAL>
__global__ __launch_bounds__(256) void k_gemm_skinny(
        const unsigned short* __restrict__ S,
        const unsigned short* __restrict__ Ht,   // [64][NN]
        const float* __restrict__ bias,
        const float* __restrict__ U1,
        float* __restrict__ Y) {
    __shared__ unsigned short Ts[2][16 * 128];   // 2 x 4 KB
    __shared__ unsigned short Hs[2][64 * 128];   // 2 x 16 KB
    int t = threadIdx.x, lane = t & 63, w = t >> 6;
    int i0 = blockIdx.x * 16;
    int r = lane & 15, kg = lane >> 4;

    // staging: thread t -> (row = t>>4, 16B chunk c = t&15), swizzled source col
    int srow = t >> 4, sc = t & 15;
    int sbyte = (sc * 16) ^ ((srow & 7) << 4);          // byte within 256B row seg
    const unsigned short* aSrc = S + (long long)(i0 + srow) * NN + (sbyte >> 1);
    const unsigned short* hSrc = Ht + (long long)srow * NN + (sbyte >> 1);
    char* tsDst0 = (char*)&Ts[0][0] + t * 16;
    char* tsDst1 = (char*)&Ts[1][0] + t * 16;
    char* hsDst0 = (char*)&Hs[0][0] + t * 16;
    char* hsDst1 = (char*)&Hs[1][0] + t * 16;

    f32x4 acc = {0.f, 0.f, 0.f, 0.f};

    // prologue: stage tile 0 into buf 0
    GL16(aSrc, tsDst0);
    #pragma unroll
    for (int q = 0; q < 4; ++q)
        GL16(hSrc + (long long)q * 16 * NN, hsDst0 + q * 4096);
    __syncthreads();

    int cur = 0;
    for (int jt = 0; jt < NN; jt += 128) {
        if (jt + 128 < NN) {                   // prefetch next into other buf
            if (cur == 0) {
                GL16(aSrc + jt + 128, tsDst1);
                #pragma unroll
                for (int q = 0; q < 4; ++q)
                    GL16(hSrc + (long long)q * 16 * NN + jt + 128, hsDst1 + q * 4096);
            } else {
                GL16(aSrc + jt + 128, tsDst0);
                #pragma unroll
                for (int q = 0; q < 4; ++q)
                    GL16(hSrc + (long long)q * 16 * NN + jt + 128, hsDst0 + q * 4096);
            }
        }
        const char* tsB = (const char*)&Ts[cur][0];
        const char* hsB = (const char*)&Hs[cur][0];
        int hr = w * 16 + r;
        #pragma unroll
        for (int kk = 0; kk < 4; ++kk) {
            int xo = kk * 64 + kg * 16;
            short8 a = *(const short8*)(tsB + r * 256 + (xo ^ ((r & 7) << 4)));
            short8 bb = *(const short8*)(hsB + hr * 256 + (xo ^ ((r & 7) << 4)));
            acc = __builtin_amdgcn_mfma_f32_16x16x32_bf16(a, bb, acc, 0, 0, 0);
        }
        __syncthreads();                       // drains vmcnt (next buf ready) + lgkm
        cur ^= 1;
    }

    // D[m = kg*4+rr][n = r] ; wave n-strip = w*16..w*16+15
    int f = w * 16 + r;
    float bv = bias[f];
    #pragma unroll
    for (int rr = 0; rr < 4; ++rr) {
        long long gi = (long long)(i0 + kg * 4 + rr) * 64 + f;
        float v = acc[rr] + bv;
        if (FINAL) v = 0.5f * (U1[gi] + v);
        Y[gi] = v;
    }
}

// ---------------------------------------------------------------------------
extern "C" void kernel_launch(void* const* d_in, const int* in_sizes, int n_in,
                              void* d_out, int out_size, void* d_ws, size_t ws_size,
                              hipStream_t stream) {
    const float* A    = (const float*)d_in[0];
    const float* feat = (const float*)d_in[1];
    const float* wb   = (const float*)d_in[2];
    const float* W1   = (const float*)d_in[3];
    const float* b1   = (const float*)d_in[4];
    const float* W2   = (const float*)d_in[5];
    const float* b2   = (const float*)d_in[6];
    float* out = (float*)d_out;

    const size_t szS = (size_t)NN * NN * 2;       // 128 MB bf16 S
    const size_t szH = (size_t)64 * NN * 2;       // 1 MB  bf16 Ht
    char* p = (char*)d_ws;
    unsigned short* S   = (unsigned short*)p;
    unsigned short* H1t = (unsigned short*)(p + szS);
    unsigned short* H2t = (unsigned short*)(p + szS + szH);
    float*          U1  = (float*)(p + szS + 2 * szH);

    k_sym_build<<<8256, 256, 0, stream>>>(A, wb, S);
    k_small_gemm_t<<<128, 256, 0, stream>>>(feat, W1, H1t);
    k_gemm_skinny<0><<<512, 256, 0, stream>>>(S, H1t, b1, nullptr, U1);
    k_small_gemm_t<<<128, 256, 0, stream>>>(U1, W2, H2t);
    k_gemm_skinny<1><<<512, 256, 0, stream>>>(S, H2t, b2, U1, out);
}